// Round 21
// baseline (123.067 us; speedup 1.0000x reference)
//
#include <hip/hip_runtime.h>
#include <math.h>

#define NUM_B 4
#define NUM_N 20000
#define NUM_E 100000
#define DIM 128
#define NH 8
#define NHD 16
#define BN (NUM_B * NUM_N)
#define NB ((BN + 255) / 256)
#define CAP 32                 // max in-degree bucket (Poisson(5), max~18)
#define XPAD 132               // padded LDS row stride (floats)
#define APAD 136               // padded LDS row stride (ushorts), k_out
#define LOG2E 1.44269504088896f
#define PROJ_BLOCKS (BN / 64)  // 1250
#define SCAT_BLOCKS 391        // 4 grid-stride edges per thread

typedef unsigned short ushort_t;
typedef __attribute__((ext_vector_type(8))) short bf16x8;
typedef __attribute__((ext_vector_type(4))) float f32x4;

union ABFrag {
  bf16x8 v;
  ushort4 h[2];
};

__device__ inline ushort_t f2bf(float f) {
  unsigned u = __float_as_uint(f);
  unsigned r = (u + 0x7FFFu + ((u >> 16) & 1u)) >> 16;  // RNE
  return (ushort_t)r;
}

__device__ inline float bf2f_lo(unsigned v) {
  return __uint_as_float((v & 0xFFFFu) << 16);
}
__device__ inline float bf2f_hi(unsigned v) {
  return __uint_as_float(v & 0xFFFF0000u);
}

// ------------- init (fat): blocks<NB zero cursors; block NB does prep ----
__global__ __launch_bounds__(256) void k_init(
    const float* __restrict__ Wq, const float* __restrict__ bq,
    const float* __restrict__ Wk, const float* __restrict__ bk,
    const float* __restrict__ attn, const float* __restrict__ Wv,
    const float* __restrict__ Wo,
    float* __restrict__ AqT, float* __restrict__ AkT,
    float* __restrict__ cvec,
    ushort_t* __restrict__ Wb, ushort_t* __restrict__ WoB,
    int* __restrict__ cursor) {
  int t = threadIdx.x;
  if (blockIdx.x < NB) {
    int i = blockIdx.x * 256 + t;
    if (i < BN) cursor[i] = 0;
    return;
  }
  // prep body (single block)
  for (int idx = t; idx < DIM * NH; idx += 256) {
    int h = idx >> 7, i = idx & 127;
    float sq = 0.f, sk = 0.f;
    for (int d = 0; d < NHD; ++d) {
      sq += Wq[i * DIM + h * NHD + d] * attn[h * 2 * NHD + d];
      sk += Wk[i * DIM + h * NHD + d] * attn[h * 2 * NHD + NHD + d];
    }
    AqT[idx] = sq;  // [h][128]
    AkT[idx] = sk;
  }
  if (t < NH) {
    float cq = 0.f, ck = 0.f;
    for (int d = 0; d < NHD; ++d) {
      cq += bq[t * NHD + d] * attn[t * 2 * NHD + d];
      ck += bk[t * NHD + d] * attn[t * 2 * NHD + NHD + d];
    }
    cvec[t] = cq;
    cvec[NH + t] = ck;
  }
  for (int idx = t; idx < 8 * 4 * 64 * 8; idx += 256) {
    int e = idx & 7;
    int l = (idx >> 3) & 63;
    int ks = (idx >> 9) & 3;
    int ct = idx >> 11;
    int krow = ks * 32 + ((l >> 4) << 2) + (e & 3) + ((e >> 2) << 4);
    int cc = ct * 16 + (l & 15);
    Wb[idx] = f2bf(Wv[krow * DIM + cc]);
    WoB[idx] = f2bf(Wo[krow * DIM + cc]);
  }
}

// ------------- fat kernel: proj (blocks<1250) + bucket scatter ----------
// LDS = xs only (33.8KB) -> 4 blocks/CU (A tables read direct from
// global; 8KB, L1-resident, 8-lane broadcast b128).
__global__ __launch_bounds__(256) void k_fat(
    const float* __restrict__ X, const ushort_t* __restrict__ Wb,
    const float* __restrict__ bv, const float* __restrict__ AqT,
    const float* __restrict__ AkT, const float* __restrict__ cvec,
    float* __restrict__ aq, float* __restrict__ ak, ushort_t* __restrict__ V,
    const int* __restrict__ eidx, int* __restrict__ cursor,
    int* __restrict__ bucket) {
  int t = threadIdx.x;
  if (blockIdx.x >= PROJ_BLOCKS) {
    // ---- scatter branch: 4 grid-stride edges per thread ----
    int base = (blockIdx.x - PROJ_BLOCKS) * 256 + t;
    for (int gid = base; gid < NUM_B * NUM_E; gid += SCAT_BLOCKS * 256) {
      int b = gid / NUM_E, e = gid - b * NUM_E;
      int src = eidx[b * 2 * NUM_E + e];
      int tgt = eidx[b * 2 * NUM_E + NUM_E + e];
      int seg = b * NUM_N + tgt;
      int pos = atomicAdd(&cursor[seg], 1);
      if (pos < CAP) bucket[seg * CAP + pos] = b * NUM_N + src;
    }
    return;
  }
  // ---- proj branch ----
  __shared__ float xs[64][XPAD];
  int node0 = blockIdx.x * 64;
  int w = t >> 6, l = t & 63;
  int lr = l & 15, lg = l >> 4;
  int row0 = w * 16;

  const float4* Xv = (const float4*)(X + (int64_t)node0 * DIM);
  for (int k = t; k < 64 * 32; k += 256) {
    int n = k >> 5, c = k & 31;
    ((float4*)&xs[n][0])[c] = Xv[k];
  }
  __syncthreads();

  // A-fragments (m89/m162): lane l row = l&15, k = (l>>4)*4+(e&3)+16*(e>>2)
  ABFrag af[4];
#pragma unroll
  for (int ks = 0; ks < 4; ++ks) {
    float4 xa = *(const float4*)&xs[row0 + lr][ks * 32 + lg * 4];
    float4 xb = *(const float4*)&xs[row0 + lr][ks * 32 + 16 + lg * 4];
    ushort4 ua, ub;
    ua.x = f2bf(xa.x); ua.y = f2bf(xa.y); ua.z = f2bf(xa.z); ua.w = f2bf(xa.w);
    ub.x = f2bf(xb.x); ub.y = f2bf(xb.y); ub.z = f2bf(xb.z); ub.w = f2bf(xb.w);
    af[ks].h[0] = ua;
    af[ks].h[1] = ub;
  }

  // V col-tiles via MFMA; D mapping: col = l&15, row = (l>>4)*4 + reg.
  const bf16x8* WbF = (const bf16x8*)Wb;
#pragma unroll
  for (int ct = 0; ct < 8; ++ct) {
    f32x4 acc = {0.f, 0.f, 0.f, 0.f};
#pragma unroll
    for (int ks = 0; ks < 4; ++ks) {
      bf16x8 b = WbF[(ct * 4 + ks) * 64 + l];
      acc = __builtin_amdgcn_mfma_f32_16x16x32_bf16(af[ks].v, b, acc, 0, 0, 0);
    }
    float bvc = bv[ct * 16 + lr];
#pragma unroll
    for (int r = 0; r < 4; ++r) {
      int row = node0 + row0 + lg * 4 + r;
      V[(int64_t)row * DIM + ct * 16 + lr] = f2bf(acc[r] + bvc);
    }
  }

  // aq/ak tail: 256 tasks (node-pair, h); x from LDS (b128), A tables
  // direct from global ([h][128] compact, 8-lane broadcast).
  {
    int h = t & 7, np = t >> 3;
    const float4* x0 = (const float4*)&xs[2 * np][0];
    const float4* x1 = (const float4*)&xs[2 * np + 1][0];
    const float4* wq4 = (const float4*)(AqT + h * DIM);
    const float4* wk4 = (const float4*)(AkT + h * DIM);
    float cq = cvec[h], ck = cvec[NH + h];
    float sq0 = 0.f, sk0 = 0.f, sq1 = 0.f, sk1 = 0.f;
#pragma unroll 8
    for (int i4 = 0; i4 < 32; ++i4) {
      float4 xa = x0[i4];
      float4 xb = x1[i4];
      float4 wq = wq4[i4];
      float4 wk = wk4[i4];
      sq0 += xa.x * wq.x + xa.y * wq.y + xa.z * wq.z + xa.w * wq.w;
      sk0 += xa.x * wk.x + xa.y * wk.y + xa.z * wk.z + xa.w * wk.w;
      sq1 += xb.x * wq.x + xb.y * wq.y + xb.z * wq.z + xb.w * wq.w;
      sk1 += xb.x * wk.x + xb.y * wk.y + xb.z * wk.z + xb.w * wk.w;
    }
    int r0 = (node0 + 2 * np) * NH + h;
    aq[r0] = (sq0 + cq) * LOG2E;
    ak[r0] = (sk0 + ck) * LOG2E;
    aq[r0 + NH] = (sq1 + cq) * LOG2E;
    ak[r0 + NH] = (sk1 + ck) * LOG2E;
  }
}

// ------------- gather: speculative first-8-edge prefetch ----------------
__global__ __launch_bounds__(256) void k_gather(
    const int* __restrict__ bucket, const int* __restrict__ cursor,
    const float* __restrict__ aq, const float* __restrict__ ak,
    const ushort_t* __restrict__ V, ushort_t* __restrict__ agg) {
  int tid = threadIdx.x;
  int node = blockIdx.x * 4 + (tid >> 6);
  int l = tid & 63;
  int half = l >> 5, c = l & 31;
  int h = c >> 2;
  const int* bk = bucket + node * CAP;

  int cnt = cursor[node];
  int sfr[4];
#pragma unroll
  for (int i = 0; i < 4; ++i) sfr[i] = bk[2 * i + half];
  float aqh = aq[node * NH + h];
#pragma unroll
  for (int i = 0; i < 4; ++i) {
    int s = sfr[i];
    s = s < 0 ? 0 : s;
    sfr[i] = s > BN - 1 ? BN - 1 : s;
  }

  float a0 = 0.f, a1 = 0.f, a2 = 0.f, a3 = 0.f, den = 0.f;
  cnt = cnt < CAP ? cnt : CAP;
#pragma unroll
  for (int i = 0; i < 4; ++i) {
    int sf = sfr[i];
    float av = ak[sf * NH + h];
    float2 v = *(const float2*)((const unsigned*)(V + ((int64_t)sf << 7)) +
                                2 * c);
    unsigned u0 = __float_as_uint(v.x), u1 = __float_as_uint(v.y);
    float s = aqh + av;
    s = fmaxf(s, 0.2f * s);
    float e = (2 * i + half < cnt) ? exp2f(s) : 0.f;
    a0 += e * bf2f_lo(u0);
    a1 += e * bf2f_hi(u0);
    a2 += e * bf2f_lo(u1);
    a3 += e * bf2f_hi(u1);
    den += e;
  }

  // rare tail: degree > 8
  for (int p = 8 + half; p < cnt; p += 2) {
    int sf = bk[p];
    float av = ak[sf * NH + h];
    float2 v = *(const float2*)((const unsigned*)(V + ((int64_t)sf << 7)) +
                                2 * c);
    unsigned u0 = __float_as_uint(v.x), u1 = __float_as_uint(v.y);
    float s = aqh + av;
    s = fmaxf(s, 0.2f * s);
    float e = exp2f(s);
    a0 += e * bf2f_lo(u0);
    a1 += e * bf2f_hi(u0);
    a2 += e * bf2f_lo(u1);
    a3 += e * bf2f_hi(u1);
    den += e;
  }

  a0 += __shfl_xor(a0, 32);
  a1 += __shfl_xor(a1, 32);
  a2 += __shfl_xor(a2, 32);
  a3 += __shfl_xor(a3, 32);
  den += __shfl_xor(den, 32);
  if (half == 0) {
    float inv = den > 0.f ? 1.0f / den : 0.f;
    unsigned o0 = ((unsigned)f2bf(a1 * inv) << 16) | f2bf(a0 * inv);
    unsigned o1 = ((unsigned)f2bf(a3 * inv) << 16) | f2bf(a2 * inv);
    uint2 o;
    o.x = o0;
    o.y = o1;
    *(uint2*)((unsigned*)(agg + ((int64_t)node << 7)) + 2 * c) = o;
  }
}

// ------------- epilogue (MFMA): out = LN(agg @ Wo + bo + X) -------------
__global__ __launch_bounds__(256) void k_out(
    const ushort_t* __restrict__ agg, const ushort_t* __restrict__ WoB,
    const float* __restrict__ X, const float* __restrict__ bo,
    const float* __restrict__ gamma, const float* __restrict__ beta,
    float* __restrict__ out) {
  __shared__ ushort_t as[64][APAD];
  int t = threadIdx.x;
  int node0 = blockIdx.x * 64;
  int w = t >> 6, l = t & 63;
  int lr = l & 15, lg = l >> 4;
  int row0 = w * 16;

  // stage agg tile: 64 rows x 128 bf16 = 64 rows x 64 u32
  const unsigned* Ag = (const unsigned*)(agg + ((int64_t)node0 << 7));
  for (int k = t; k < 64 * 64; k += 256) {
    int n = k >> 6, c = k & 63;
    *(unsigned*)&as[n][c * 2] = Ag[k];
  }
  __syncthreads();

  ABFrag af[4];
#pragma unroll
  for (int ks = 0; ks < 4; ++ks) {
    af[ks].h[0] = *(const ushort4*)&as[row0 + lr][ks * 32 + lg * 4];
    af[ks].h[1] = *(const ushort4*)&as[row0 + lr][ks * 32 + 16 + lg * 4];
  }

  const bf16x8* WoF = (const bf16x8*)WoB;
  float vals[8][4];  // [ct][r]
#pragma unroll
  for (int ct = 0; ct < 8; ++ct) {
    f32x4 acc = {0.f, 0.f, 0.f, 0.f};
#pragma unroll
    for (int ks = 0; ks < 4; ++ks) {
      bf16x8 b = WoF[(ct * 4 + ks) * 64 + l];
      acc = __builtin_amdgcn_mfma_f32_16x16x32_bf16(af[ks].v, b, acc, 0, 0, 0);
    }
    float boc = bo[ct * 16 + lr];
#pragma unroll
    for (int r = 0; r < 4; ++r) {
      int row = node0 + row0 + lg * 4 + r;
      vals[ct][r] = acc[r] + boc + X[(int64_t)row * DIM + ct * 16 + lr];
    }
  }

  // LN: row (lg*4+r) lives across the 16 lanes sharing lg
  float s1[4], s2[4];
#pragma unroll
  for (int r = 0; r < 4; ++r) {
    float a = 0.f, b2 = 0.f;
#pragma unroll
    for (int ct = 0; ct < 8; ++ct) {
      a += vals[ct][r];
      b2 += vals[ct][r] * vals[ct][r];
    }
    s1[r] = a;
    s2[r] = b2;
  }
#pragma unroll
  for (int off = 1; off < 16; off <<= 1) {
#pragma unroll
    for (int r = 0; r < 4; ++r) {
      s1[r] += __shfl_xor(s1[r], off);
      s2[r] += __shfl_xor(s2[r], off);
    }
  }
  float mu[4], rs[4];
#pragma unroll
  for (int r = 0; r < 4; ++r) {
    mu[r] = s1[r] * (1.0f / DIM);
    float var = s2[r] * (1.0f / DIM) - mu[r] * mu[r];
    rs[r] = rsqrtf(var + 1e-5f);
  }
#pragma unroll
  for (int ct = 0; ct < 8; ++ct) {
    float gm = gamma[ct * 16 + lr], bt = beta[ct * 16 + lr];
#pragma unroll
    for (int r = 0; r < 4; ++r) {
      int row = node0 + row0 + lg * 4 + r;
      out[(int64_t)row * DIM + ct * 16 + lr] =
          (vals[ct][r] - mu[r]) * rs[r] * gm + bt;
    }
  }
}

extern "C" void kernel_launch(void* const* d_in, const int* in_sizes, int n_in,
                              void* d_out, int out_size, void* d_ws,
                              size_t ws_size, hipStream_t stream) {
  const float* X     = (const float*)d_in[0];
  const int*   eidx  = (const int*)d_in[1];
  const float* Wq    = (const float*)d_in[2];
  const float* bq    = (const float*)d_in[3];
  const float* Wk    = (const float*)d_in[4];
  const float* bk    = (const float*)d_in[5];
  const float* Wv    = (const float*)d_in[6];
  const float* bv    = (const float*)d_in[7];
  const float* attn  = (const float*)d_in[8];
  const float* Wo    = (const float*)d_in[9];
  const float* bo    = (const float*)d_in[10];
  const float* gamma = (const float*)d_in[11];
  const float* beta  = (const float*)d_in[12];
  float* out = (float*)d_out;

  float* ws    = (float*)d_ws;
  ushort_t* Wb  = (ushort_t*)ws;          // 16384 ushorts (Wv frags)
  ushort_t* WoB = Wb + 16384;             // 16384 ushorts (Wo frags)
  float* AqT  = ws + 16384;               // 1024, layout [h][128]
  float* AkT  = AqT + 1024;               // 1024
  float* cvec = AkT + 1024;               // 16
  float* aqv  = cvec + 16;                // BN*NH
  float* akv  = aqv + (int64_t)BN * NH;   // BN*NH
  ushort_t* V   = (ushort_t*)(akv + (int64_t)BN * NH);  // BN*DIM bf16
  ushort_t* agg = V + (int64_t)BN * DIM;                // BN*DIM bf16
  int* cursor = (int*)(agg + (int64_t)BN * DIM);        // BN
  int* bucket = cursor + BN;                            // BN*CAP

  k_init<<<NB + 1, 256, 0, stream>>>(Wq, bq, Wk, bk, attn, Wv, Wo, AqT, AkT,
                                     cvec, Wb, WoB, cursor);
  k_fat<<<PROJ_BLOCKS + SCAT_BLOCKS, 256, 0, stream>>>(
      X, Wb, bv, AqT, AkT, cvec, aqv, akv, V, eidx, cursor, bucket);
  k_gather<<<BN / 4, 256, 0, stream>>>(bucket, cursor, aqv, akv, V, agg);
  k_out<<<BN / 64, 256, 0, stream>>>(agg, WoB, X, bo, gamma, beta, out);
}

// Round 22
// 103.596 us; speedup vs baseline: 1.1879x; 1.1879x over previous
//
#include <hip/hip_runtime.h>
#include <math.h>

#define NUM_B 4
#define NUM_N 20000
#define NUM_E 100000
#define DIM 128
#define NH 8
#define NHD 16
#define BN (NUM_B * NUM_N)
#define NB ((BN + 255) / 256)
#define CAP 32                 // max in-degree bucket (Poisson(5), max~18)
#define XPAD 132               // padded LDS row stride (floats)
#define APITCH 132             // padded LDS row stride for A tables (floats)
#define APAD 136               // padded LDS row stride (ushorts), k_out
#define LOG2E 1.44269504088896f
#define PROJ_BLOCKS (BN / 64)  // 1250
#define SCAT_BLOCKS 391        // 4 grid-stride edges per thread; run FIRST

typedef unsigned short ushort_t;
typedef __attribute__((ext_vector_type(8))) short bf16x8;
typedef __attribute__((ext_vector_type(4))) float f32x4;

union ABFrag {
  bf16x8 v;
  ushort4 h[2];
};

__device__ inline ushort_t f2bf(float f) {
  unsigned u = __float_as_uint(f);
  unsigned r = (u + 0x7FFFu + ((u >> 16) & 1u)) >> 16;  // RNE
  return (ushort_t)r;
}

__device__ inline float bf2f_lo(unsigned v) {
  return __uint_as_float((v & 0xFFFFu) << 16);
}
__device__ inline float bf2f_hi(unsigned v) {
  return __uint_as_float(v & 0xFFFF0000u);
}

// ------------- init (fat): blocks<NB zero cursors; block NB does prep ----
__global__ __launch_bounds__(256) void k_init(
    const float* __restrict__ Wq, const float* __restrict__ bq,
    const float* __restrict__ Wk, const float* __restrict__ bk,
    const float* __restrict__ attn, const float* __restrict__ Wv,
    const float* __restrict__ Wo,
    float* __restrict__ AqT, float* __restrict__ AkT,
    float* __restrict__ cvec,
    ushort_t* __restrict__ Wb, ushort_t* __restrict__ WoB,
    int* __restrict__ cursor) {
  int t = threadIdx.x;
  if (blockIdx.x < NB) {
    int i = blockIdx.x * 256 + t;
    if (i < BN) cursor[i] = 0;
    return;
  }
  // prep body (single block)
  for (int idx = t; idx < DIM * NH; idx += 256) {
    int h = idx >> 7, i = idx & 127;
    float sq = 0.f, sk = 0.f;
    for (int d = 0; d < NHD; ++d) {
      sq += Wq[i * DIM + h * NHD + d] * attn[h * 2 * NHD + d];
      sk += Wk[i * DIM + h * NHD + d] * attn[h * 2 * NHD + NHD + d];
    }
    AqT[idx] = sq;  // [h][128]
    AkT[idx] = sk;
  }
  if (t < NH) {
    float cq = 0.f, ck = 0.f;
    for (int d = 0; d < NHD; ++d) {
      cq += bq[t * NHD + d] * attn[t * 2 * NHD + d];
      ck += bk[t * NHD + d] * attn[t * 2 * NHD + NHD + d];
    }
    cvec[t] = cq;
    cvec[NH + t] = ck;
  }
  for (int idx = t; idx < 8 * 4 * 64 * 8; idx += 256) {
    int e = idx & 7;
    int l = (idx >> 3) & 63;
    int ks = (idx >> 9) & 3;
    int ct = idx >> 11;
    int krow = ks * 32 + ((l >> 4) << 2) + (e & 3) + ((e >> 2) << 4);
    int cc = ct * 16 + (l & 15);
    Wb[idx] = f2bf(Wv[krow * DIM + cc]);
    WoB[idx] = f2bf(Wo[krow * DIM + cc]);
  }
}

// ------------- fat kernel: scatter (blocks<391, FIRST) + proj -----------
// Scatter blocks dispatch first so their atomic latency hides under
// co-resident proj MFMA work; the kernel drains on dense proj compute.
__global__ __launch_bounds__(256) void k_fat(
    const float* __restrict__ X, const ushort_t* __restrict__ Wb,
    const float* __restrict__ bv, const float* __restrict__ AqT,
    const float* __restrict__ AkT, const float* __restrict__ cvec,
    float* __restrict__ aq, float* __restrict__ ak, ushort_t* __restrict__ V,
    const int* __restrict__ eidx, int* __restrict__ cursor,
    int* __restrict__ bucket) {
  int t = threadIdx.x;
  if (blockIdx.x < SCAT_BLOCKS) {
    // ---- scatter branch: 4 grid-stride edges per thread ----
    int base = blockIdx.x * 256 + t;
    for (int gid = base; gid < NUM_B * NUM_E; gid += SCAT_BLOCKS * 256) {
      int b = gid / NUM_E, e = gid - b * NUM_E;
      int src = eidx[b * 2 * NUM_E + e];
      int tgt = eidx[b * 2 * NUM_E + NUM_E + e];
      int seg = b * NUM_N + tgt;
      int pos = atomicAdd(&cursor[seg], 1);
      if (pos < CAP) bucket[seg * CAP + pos] = b * NUM_N + src;
    }
    return;
  }
  // ---- proj branch ----
  __shared__ float xs[64][XPAD];
  __shared__ float AqS[NH * APITCH];
  __shared__ float AkS[NH * APITCH];
  int node0 = (blockIdx.x - SCAT_BLOCKS) * 64;
  int w = t >> 6, l = t & 63;
  int lr = l & 15, lg = l >> 4;
  int row0 = w * 16;

  const float4* Xv = (const float4*)(X + (int64_t)node0 * DIM);
  for (int k = t; k < 64 * 32; k += 256) {
    int n = k >> 5, c = k & 31;
    ((float4*)&xs[n][0])[c] = Xv[k];
  }
  for (int k = t; k < DIM * NH; k += 256) {
    int h = k >> 7, i = k & 127;
    AqS[h * APITCH + i] = AqT[k];
    AkS[h * APITCH + i] = AkT[k];
  }
  __syncthreads();

  // A-fragments (m89/m162): lane l row = l&15, k = (l>>4)*4+(e&3)+16*(e>>2)
  ABFrag af[4];
#pragma unroll
  for (int ks = 0; ks < 4; ++ks) {
    float4 xa = *(const float4*)&xs[row0 + lr][ks * 32 + lg * 4];
    float4 xb = *(const float4*)&xs[row0 + lr][ks * 32 + 16 + lg * 4];
    ushort4 ua, ub;
    ua.x = f2bf(xa.x); ua.y = f2bf(xa.y); ua.z = f2bf(xa.z); ua.w = f2bf(xa.w);
    ub.x = f2bf(xb.x); ub.y = f2bf(xb.y); ub.z = f2bf(xb.z); ub.w = f2bf(xb.w);
    af[ks].h[0] = ua;
    af[ks].h[1] = ub;
  }

  // V col-tiles via MFMA; D mapping: col = l&15, row = (l>>4)*4 + reg.
  const bf16x8* WbF = (const bf16x8*)Wb;
#pragma unroll
  for (int ct = 0; ct < 8; ++ct) {
    f32x4 acc = {0.f, 0.f, 0.f, 0.f};
#pragma unroll
    for (int ks = 0; ks < 4; ++ks) {
      bf16x8 b = WbF[(ct * 4 + ks) * 64 + l];
      acc = __builtin_amdgcn_mfma_f32_16x16x32_bf16(af[ks].v, b, acc, 0, 0, 0);
    }
    float bvc = bv[ct * 16 + lr];
#pragma unroll
    for (int r = 0; r < 4; ++r) {
      int row = node0 + row0 + lg * 4 + r;
      V[(int64_t)row * DIM + ct * 16 + lr] = f2bf(acc[r] + bvc);
    }
  }

  // aq/ak tail: 256 tasks (node-pair, h); b128 reads; A shared by 2 rows.
  {
    int h = t & 7, np = t >> 3;
    const float4* x0 = (const float4*)&xs[2 * np][0];
    const float4* x1 = (const float4*)&xs[2 * np + 1][0];
    const float4* wq4 = (const float4*)&AqS[h * APITCH];
    const float4* wk4 = (const float4*)&AkS[h * APITCH];
    float cq = cvec[h], ck = cvec[NH + h];
    float sq0 = 0.f, sk0 = 0.f, sq1 = 0.f, sk1 = 0.f;
#pragma unroll 8
    for (int i4 = 0; i4 < 32; ++i4) {
      float4 xa = x0[i4];
      float4 xb = x1[i4];
      float4 wq = wq4[i4];
      float4 wk = wk4[i4];
      sq0 += xa.x * wq.x + xa.y * wq.y + xa.z * wq.z + xa.w * wq.w;
      sk0 += xa.x * wk.x + xa.y * wk.y + xa.z * wk.z + xa.w * wk.w;
      sq1 += xb.x * wq.x + xb.y * wq.y + xb.z * wq.z + xb.w * wq.w;
      sk1 += xb.x * wk.x + xb.y * wk.y + xb.z * wk.z + xb.w * wk.w;
    }
    int r0 = (node0 + 2 * np) * NH + h;
    aq[r0] = (sq0 + cq) * LOG2E;
    ak[r0] = (sk0 + ck) * LOG2E;
    aq[r0 + NH] = (sq1 + cq) * LOG2E;
    ak[r0 + NH] = (sk1 + ck) * LOG2E;
  }
}

// ------------- gather: speculative first-8-edge prefetch ----------------
__global__ __launch_bounds__(256) void k_gather(
    const int* __restrict__ bucket, const int* __restrict__ cursor,
    const float* __restrict__ aq, const float* __restrict__ ak,
    const ushort_t* __restrict__ V, ushort_t* __restrict__ agg) {
  int tid = threadIdx.x;
  int node = blockIdx.x * 4 + (tid >> 6);
  int l = tid & 63;
  int half = l >> 5, c = l & 31;
  int h = c >> 2;
  const int* bk = bucket + node * CAP;

  int cnt = cursor[node];
  int sfr[4];
#pragma unroll
  for (int i = 0; i < 4; ++i) sfr[i] = bk[2 * i + half];
  float aqh = aq[node * NH + h];
#pragma unroll
  for (int i = 0; i < 4; ++i) {
    int s = sfr[i];
    s = s < 0 ? 0 : s;
    sfr[i] = s > BN - 1 ? BN - 1 : s;
  }

  float a0 = 0.f, a1 = 0.f, a2 = 0.f, a3 = 0.f, den = 0.f;
  cnt = cnt < CAP ? cnt : CAP;
#pragma unroll
  for (int i = 0; i < 4; ++i) {
    int sf = sfr[i];
    float av = ak[sf * NH + h];
    float2 v = *(const float2*)((const unsigned*)(V + ((int64_t)sf << 7)) +
                                2 * c);
    unsigned u0 = __float_as_uint(v.x), u1 = __float_as_uint(v.y);
    float s = aqh + av;
    s = fmaxf(s, 0.2f * s);
    float e = (2 * i + half < cnt) ? exp2f(s) : 0.f;
    a0 += e * bf2f_lo(u0);
    a1 += e * bf2f_hi(u0);
    a2 += e * bf2f_lo(u1);
    a3 += e * bf2f_hi(u1);
    den += e;
  }

  // rare tail: degree > 8
  for (int p = 8 + half; p < cnt; p += 2) {
    int sf = bk[p];
    float av = ak[sf * NH + h];
    float2 v = *(const float2*)((const unsigned*)(V + ((int64_t)sf << 7)) +
                                2 * c);
    unsigned u0 = __float_as_uint(v.x), u1 = __float_as_uint(v.y);
    float s = aqh + av;
    s = fmaxf(s, 0.2f * s);
    float e = exp2f(s);
    a0 += e * bf2f_lo(u0);
    a1 += e * bf2f_hi(u0);
    a2 += e * bf2f_lo(u1);
    a3 += e * bf2f_hi(u1);
    den += e;
  }

  a0 += __shfl_xor(a0, 32);
  a1 += __shfl_xor(a1, 32);
  a2 += __shfl_xor(a2, 32);
  a3 += __shfl_xor(a3, 32);
  den += __shfl_xor(den, 32);
  if (half == 0) {
    float inv = den > 0.f ? 1.0f / den : 0.f;
    unsigned o0 = ((unsigned)f2bf(a1 * inv) << 16) | f2bf(a0 * inv);
    unsigned o1 = ((unsigned)f2bf(a3 * inv) << 16) | f2bf(a2 * inv);
    uint2 o;
    o.x = o0;
    o.y = o1;
    *(uint2*)((unsigned*)(agg + ((int64_t)node << 7)) + 2 * c) = o;
  }
}

// ------------- epilogue (MFMA): out = LN(agg @ Wo + bo + X) -------------
__global__ __launch_bounds__(256) void k_out(
    const ushort_t* __restrict__ agg, const ushort_t* __restrict__ WoB,
    const float* __restrict__ X, const float* __restrict__ bo,
    const float* __restrict__ gamma, const float* __restrict__ beta,
    float* __restrict__ out) {
  __shared__ ushort_t as[64][APAD];
  int t = threadIdx.x;
  int node0 = blockIdx.x * 64;
  int w = t >> 6, l = t & 63;
  int lr = l & 15, lg = l >> 4;
  int row0 = w * 16;

  // stage agg tile: 64 rows x 128 bf16 = 64 rows x 64 u32
  const unsigned* Ag = (const unsigned*)(agg + ((int64_t)node0 << 7));
  for (int k = t; k < 64 * 64; k += 256) {
    int n = k >> 6, c = k & 63;
    *(unsigned*)&as[n][c * 2] = Ag[k];
  }
  __syncthreads();

  ABFrag af[4];
#pragma unroll
  for (int ks = 0; ks < 4; ++ks) {
    af[ks].h[0] = *(const ushort4*)&as[row0 + lr][ks * 32 + lg * 4];
    af[ks].h[1] = *(const ushort4*)&as[row0 + lr][ks * 32 + 16 + lg * 4];
  }

  const bf16x8* WoF = (const bf16x8*)WoB;
  float vals[8][4];  // [ct][r]
#pragma unroll
  for (int ct = 0; ct < 8; ++ct) {
    f32x4 acc = {0.f, 0.f, 0.f, 0.f};
#pragma unroll
    for (int ks = 0; ks < 4; ++ks) {
      bf16x8 b = WoF[(ct * 4 + ks) * 64 + l];
      acc = __builtin_amdgcn_mfma_f32_16x16x32_bf16(af[ks].v, b, acc, 0, 0, 0);
    }
    float boc = bo[ct * 16 + lr];
#pragma unroll
    for (int r = 0; r < 4; ++r) {
      int row = node0 + row0 + lg * 4 + r;
      vals[ct][r] = acc[r] + boc + X[(int64_t)row * DIM + ct * 16 + lr];
    }
  }

  // LN: row (lg*4+r) lives across the 16 lanes sharing lg
  float s1[4], s2[4];
#pragma unroll
  for (int r = 0; r < 4; ++r) {
    float a = 0.f, b2 = 0.f;
#pragma unroll
    for (int ct = 0; ct < 8; ++ct) {
      a += vals[ct][r];
      b2 += vals[ct][r] * vals[ct][r];
    }
    s1[r] = a;
    s2[r] = b2;
  }
#pragma unroll
  for (int off = 1; off < 16; off <<= 1) {
#pragma unroll
    for (int r = 0; r < 4; ++r) {
      s1[r] += __shfl_xor(s1[r], off);
      s2[r] += __shfl_xor(s2[r], off);
    }
  }
  float mu[4], rs[4];
#pragma unroll
  for (int r = 0; r < 4; ++r) {
    mu[r] = s1[r] * (1.0f / DIM);
    float var = s2[r] * (1.0f / DIM) - mu[r] * mu[r];
    rs[r] = rsqrtf(var + 1e-5f);
  }
#pragma unroll
  for (int ct = 0; ct < 8; ++ct) {
    float gm = gamma[ct * 16 + lr], bt = beta[ct * 16 + lr];
#pragma unroll
    for (int r = 0; r < 4; ++r) {
      int row = node0 + row0 + lg * 4 + r;
      out[(int64_t)row * DIM + ct * 16 + lr] =
          (vals[ct][r] - mu[r]) * rs[r] * gm + bt;
    }
  }
}

extern "C" void kernel_launch(void* const* d_in, const int* in_sizes, int n_in,
                              void* d_out, int out_size, void* d_ws,
                              size_t ws_size, hipStream_t stream) {
  const float* X     = (const float*)d_in[0];
  const int*   eidx  = (const int*)d_in[1];
  const float* Wq    = (const float*)d_in[2];
  const float* bq    = (const float*)d_in[3];
  const float* Wk    = (const float*)d_in[4];
  const float* bk    = (const float*)d_in[5];
  const float* Wv    = (const float*)d_in[6];
  const float* bv    = (const float*)d_in[7];
  const float* attn  = (const float*)d_in[8];
  const float* Wo    = (const float*)d_in[9];
  const float* bo    = (const float*)d_in[10];
  const float* gamma = (const float*)d_in[11];
  const float* beta  = (const float*)d_in[12];
  float* out = (float*)d_out;

  float* ws    = (float*)d_ws;
  ushort_t* Wb  = (ushort_t*)ws;          // 16384 ushorts (Wv frags)
  ushort_t* WoB = Wb + 16384;             // 16384 ushorts (Wo frags)
  float* AqT  = ws + 16384;               // 1024, layout [h][128]
  float* AkT  = AqT + 1024;               // 1024
  float* cvec = AkT + 1024;               // 16
  float* aqv  = cvec + 16;                // BN*NH
  float* akv  = aqv + (int64_t)BN * NH;   // BN*NH
  ushort_t* V   = (ushort_t*)(akv + (int64_t)BN * NH);  // BN*DIM bf16
  ushort_t* agg = V + (int64_t)BN * DIM;                // BN*DIM bf16
  int* cursor = (int*)(agg + (int64_t)BN * DIM);        // BN
  int* bucket = cursor + BN;                            // BN*CAP

  k_init<<<NB + 1, 256, 0, stream>>>(Wq, bq, Wk, bk, attn, Wv, Wo, AqT, AkT,
                                     cvec, Wb, WoB, cursor);
  k_fat<<<PROJ_BLOCKS + SCAT_BLOCKS, 256, 0, stream>>>(
      X, Wb, bv, AqT, AkT, cvec, aqv, akv, V, eidx, cursor, bucket);
  k_gather<<<BN / 4, 256, 0, stream>>>(bucket, cursor, aqv, akv, V, agg);
  k_out<<<BN / 64, 256, 0, stream>>>(agg, WoB, X, bo, gamma, beta, out);
}

// Round 23
// 100.524 us; speedup vs baseline: 1.2243x; 1.0306x over previous
//
#include <hip/hip_runtime.h>
#include <math.h>

#define NUM_B 4
#define NUM_N 20000
#define NUM_E 100000
#define DIM 128
#define NH 8
#define NHD 16
#define BN (NUM_B * NUM_N)
#define NB ((BN + 255) / 256)
#define CAP 32                 // max in-degree bucket (Poisson(5), max~18)
#define XPAD 132               // padded LDS row stride (floats)
#define APITCH 132             // padded LDS row stride for A tables (floats)
#define APAD 136               // padded LDS row stride (ushorts), k_out
#define LOG2E 1.44269504088896f
#define PROJ_BLOCKS (BN / 64)  // 1250
#define SCAT_BLOCKS 391        // 4 grid-stride edges per thread

typedef unsigned short ushort_t;
typedef __attribute__((ext_vector_type(8))) short bf16x8;
typedef __attribute__((ext_vector_type(4))) float f32x4;

union ABFrag {
  bf16x8 v;
  ushort4 h[2];
};

__device__ inline ushort_t f2bf(float f) {
  unsigned u = __float_as_uint(f);
  unsigned r = (u + 0x7FFFu + ((u >> 16) & 1u)) >> 16;  // RNE
  return (ushort_t)r;
}

__device__ inline float bf2f_lo(unsigned v) {
  return __uint_as_float((v & 0xFFFFu) << 16);
}
__device__ inline float bf2f_hi(unsigned v) {
  return __uint_as_float(v & 0xFFFF0000u);
}

// ------------- init (fat): blocks<NB zero cursors; block NB does prep ----
__global__ __launch_bounds__(256) void k_init(
    const float* __restrict__ Wq, const float* __restrict__ bq,
    const float* __restrict__ Wk, const float* __restrict__ bk,
    const float* __restrict__ attn, const float* __restrict__ Wv,
    const float* __restrict__ Wo,
    float* __restrict__ AqT, float* __restrict__ AkT,
    float* __restrict__ cvec,
    ushort_t* __restrict__ Wb, ushort_t* __restrict__ WoB,
    int* __restrict__ cursor) {
  int t = threadIdx.x;
  if (blockIdx.x < NB) {
    int i = blockIdx.x * 256 + t;
    if (i < BN) cursor[i] = 0;
    return;
  }
  // prep body (single block)
  for (int idx = t; idx < DIM * NH; idx += 256) {
    int h = idx >> 7, i = idx & 127;
    float sq = 0.f, sk = 0.f;
    for (int d = 0; d < NHD; ++d) {
      sq += Wq[i * DIM + h * NHD + d] * attn[h * 2 * NHD + d];
      sk += Wk[i * DIM + h * NHD + d] * attn[h * 2 * NHD + NHD + d];
    }
    AqT[idx] = sq;  // [h][128]
    AkT[idx] = sk;
  }
  if (t < NH) {
    float cq = 0.f, ck = 0.f;
    for (int d = 0; d < NHD; ++d) {
      cq += bq[t * NHD + d] * attn[t * 2 * NHD + d];
      ck += bk[t * NHD + d] * attn[t * 2 * NHD + NHD + d];
    }
    cvec[t] = cq;
    cvec[NH + t] = ck;
  }
  for (int idx = t; idx < 8 * 4 * 64 * 8; idx += 256) {
    int e = idx & 7;
    int l = (idx >> 3) & 63;
    int ks = (idx >> 9) & 3;
    int ct = idx >> 11;
    int krow = ks * 32 + ((l >> 4) << 2) + (e & 3) + ((e >> 2) << 4);
    int cc = ct * 16 + (l & 15);
    Wb[idx] = f2bf(Wv[krow * DIM + cc]);
    WoB[idx] = f2bf(Wo[krow * DIM + cc]);
  }
}

// ------------- fat kernel: proj (blocks<1250) + bucket scatter ----------
__global__ __launch_bounds__(256) void k_fat(
    const float* __restrict__ X, const ushort_t* __restrict__ Wb,
    const float* __restrict__ bv, const float* __restrict__ AqT,
    const float* __restrict__ AkT, const float* __restrict__ cvec,
    float* __restrict__ aq, float* __restrict__ ak, ushort_t* __restrict__ V,
    const int* __restrict__ eidx, int* __restrict__ cursor,
    int* __restrict__ bucket) {
  int t = threadIdx.x;
  if (blockIdx.x >= PROJ_BLOCKS) {
    // ---- scatter branch: 4 grid-stride edges per thread ----
    int base = (blockIdx.x - PROJ_BLOCKS) * 256 + t;
    for (int gid = base; gid < NUM_B * NUM_E; gid += SCAT_BLOCKS * 256) {
      int b = gid / NUM_E, e = gid - b * NUM_E;
      int src = eidx[b * 2 * NUM_E + e];
      int tgt = eidx[b * 2 * NUM_E + NUM_E + e];
      int seg = b * NUM_N + tgt;
      int pos = atomicAdd(&cursor[seg], 1);
      if (pos < CAP) bucket[seg * CAP + pos] = b * NUM_N + src;
    }
    return;
  }
  // ---- proj branch ----
  __shared__ float xs[64][XPAD];
  __shared__ float AqS[NH * APITCH];
  __shared__ float AkS[NH * APITCH];
  int node0 = blockIdx.x * 64;
  int w = t >> 6, l = t & 63;
  int lr = l & 15, lg = l >> 4;
  int row0 = w * 16;

  const float4* Xv = (const float4*)(X + (int64_t)node0 * DIM);
  for (int k = t; k < 64 * 32; k += 256) {
    int n = k >> 5, c = k & 31;
    ((float4*)&xs[n][0])[c] = Xv[k];
  }
  for (int k = t; k < DIM * NH; k += 256) {
    int h = k >> 7, i = k & 127;
    AqS[h * APITCH + i] = AqT[k];
    AkS[h * APITCH + i] = AkT[k];
  }
  __syncthreads();

  // A-fragments (m89/m162): lane l row = l&15, k = (l>>4)*4+(e&3)+16*(e>>2)
  ABFrag af[4];
#pragma unroll
  for (int ks = 0; ks < 4; ++ks) {
    float4 xa = *(const float4*)&xs[row0 + lr][ks * 32 + lg * 4];
    float4 xb = *(const float4*)&xs[row0 + lr][ks * 32 + 16 + lg * 4];
    ushort4 ua, ub;
    ua.x = f2bf(xa.x); ua.y = f2bf(xa.y); ua.z = f2bf(xa.z); ua.w = f2bf(xa.w);
    ub.x = f2bf(xb.x); ub.y = f2bf(xb.y); ub.z = f2bf(xb.z); ub.w = f2bf(xb.w);
    af[ks].h[0] = ua;
    af[ks].h[1] = ub;
  }

  // V col-tiles via MFMA; D mapping: col = l&15, row = (l>>4)*4 + reg.
  const bf16x8* WbF = (const bf16x8*)Wb;
#pragma unroll
  for (int ct = 0; ct < 8; ++ct) {
    f32x4 acc = {0.f, 0.f, 0.f, 0.f};
#pragma unroll
    for (int ks = 0; ks < 4; ++ks) {
      bf16x8 b = WbF[(ct * 4 + ks) * 64 + l];
      acc = __builtin_amdgcn_mfma_f32_16x16x32_bf16(af[ks].v, b, acc, 0, 0, 0);
    }
    float bvc = bv[ct * 16 + lr];
#pragma unroll
    for (int r = 0; r < 4; ++r) {
      int row = node0 + row0 + lg * 4 + r;
      V[(int64_t)row * DIM + ct * 16 + lr] = f2bf(acc[r] + bvc);
    }
  }

  // aq/ak tail: 256 tasks (node-pair, h); b128 reads; A shared by 2 rows.
  {
    int h = t & 7, np = t >> 3;
    const float4* x0 = (const float4*)&xs[2 * np][0];
    const float4* x1 = (const float4*)&xs[2 * np + 1][0];
    const float4* wq4 = (const float4*)&AqS[h * APITCH];
    const float4* wk4 = (const float4*)&AkS[h * APITCH];
    float cq = cvec[h], ck = cvec[NH + h];
    float sq0 = 0.f, sk0 = 0.f, sq1 = 0.f, sk1 = 0.f;
#pragma unroll 8
    for (int i4 = 0; i4 < 32; ++i4) {
      float4 xa = x0[i4];
      float4 xb = x1[i4];
      float4 wq = wq4[i4];
      float4 wk = wk4[i4];
      sq0 += xa.x * wq.x + xa.y * wq.y + xa.z * wq.z + xa.w * wq.w;
      sk0 += xa.x * wk.x + xa.y * wk.y + xa.z * wk.z + xa.w * wk.w;
      sq1 += xb.x * wq.x + xb.y * wq.y + xb.z * wq.z + xb.w * wq.w;
      sk1 += xb.x * wk.x + xb.y * wk.y + xb.z * wk.z + xb.w * wk.w;
    }
    int r0 = (node0 + 2 * np) * NH + h;
    aq[r0] = (sq0 + cq) * LOG2E;
    ak[r0] = (sk0 + ck) * LOG2E;
    aq[r0 + NH] = (sq1 + cq) * LOG2E;
    ak[r0 + NH] = (sk1 + ck) * LOG2E;
  }
}

// ------------- gather: speculative first-8-edge prefetch ----------------
__global__ __launch_bounds__(256) void k_gather(
    const int* __restrict__ bucket, const int* __restrict__ cursor,
    const float* __restrict__ aq, const float* __restrict__ ak,
    const ushort_t* __restrict__ V, ushort_t* __restrict__ agg) {
  int tid = threadIdx.x;
  int node = blockIdx.x * 4 + (tid >> 6);
  int l = tid & 63;
  int half = l >> 5, c = l & 31;
  int h = c >> 2;
  const int* bk = bucket + node * CAP;

  int cnt = cursor[node];
  int sfr[4];
#pragma unroll
  for (int i = 0; i < 4; ++i) sfr[i] = bk[2 * i + half];
  float aqh = aq[node * NH + h];
#pragma unroll
  for (int i = 0; i < 4; ++i) {
    int s = sfr[i];
    s = s < 0 ? 0 : s;
    sfr[i] = s > BN - 1 ? BN - 1 : s;
  }

  float a0 = 0.f, a1 = 0.f, a2 = 0.f, a3 = 0.f, den = 0.f;
  cnt = cnt < CAP ? cnt : CAP;
#pragma unroll
  for (int i = 0; i < 4; ++i) {
    int sf = sfr[i];
    float av = ak[sf * NH + h];
    float2 v = *(const float2*)((const unsigned*)(V + ((int64_t)sf << 7)) +
                                2 * c);
    unsigned u0 = __float_as_uint(v.x), u1 = __float_as_uint(v.y);
    float s = aqh + av;
    s = fmaxf(s, 0.2f * s);
    float e = (2 * i + half < cnt) ? exp2f(s) : 0.f;
    a0 += e * bf2f_lo(u0);
    a1 += e * bf2f_hi(u0);
    a2 += e * bf2f_lo(u1);
    a3 += e * bf2f_hi(u1);
    den += e;
  }

  // rare tail: degree > 8
  for (int p = 8 + half; p < cnt; p += 2) {
    int sf = bk[p];
    float av = ak[sf * NH + h];
    float2 v = *(const float2*)((const unsigned*)(V + ((int64_t)sf << 7)) +
                                2 * c);
    unsigned u0 = __float_as_uint(v.x), u1 = __float_as_uint(v.y);
    float s = aqh + av;
    s = fmaxf(s, 0.2f * s);
    float e = exp2f(s);
    a0 += e * bf2f_lo(u0);
    a1 += e * bf2f_hi(u0);
    a2 += e * bf2f_lo(u1);
    a3 += e * bf2f_hi(u1);
    den += e;
  }

  a0 += __shfl_xor(a0, 32);
  a1 += __shfl_xor(a1, 32);
  a2 += __shfl_xor(a2, 32);
  a3 += __shfl_xor(a3, 32);
  den += __shfl_xor(den, 32);
  if (half == 0) {
    float inv = den > 0.f ? 1.0f / den : 0.f;
    unsigned o0 = ((unsigned)f2bf(a1 * inv) << 16) | f2bf(a0 * inv);
    unsigned o1 = ((unsigned)f2bf(a3 * inv) << 16) | f2bf(a2 * inv);
    uint2 o;
    o.x = o0;
    o.y = o1;
    *(uint2*)((unsigned*)(agg + ((int64_t)node << 7)) + 2 * c) = o;
  }
}

// ------------- epilogue (MFMA): out = LN(agg @ Wo + bo + X) -------------
__global__ __launch_bounds__(256) void k_out(
    const ushort_t* __restrict__ agg, const ushort_t* __restrict__ WoB,
    const float* __restrict__ X, const float* __restrict__ bo,
    const float* __restrict__ gamma, const float* __restrict__ beta,
    float* __restrict__ out) {
  __shared__ ushort_t as[64][APAD];
  int t = threadIdx.x;
  int node0 = blockIdx.x * 64;
  int w = t >> 6, l = t & 63;
  int lr = l & 15, lg = l >> 4;
  int row0 = w * 16;

  // stage agg tile: 64 rows x 128 bf16 = 64 rows x 64 u32
  const unsigned* Ag = (const unsigned*)(agg + ((int64_t)node0 << 7));
  for (int k = t; k < 64 * 64; k += 256) {
    int n = k >> 6, c = k & 63;
    *(unsigned*)&as[n][c * 2] = Ag[k];
  }
  __syncthreads();

  ABFrag af[4];
#pragma unroll
  for (int ks = 0; ks < 4; ++ks) {
    af[ks].h[0] = *(const ushort4*)&as[row0 + lr][ks * 32 + lg * 4];
    af[ks].h[1] = *(const ushort4*)&as[row0 + lr][ks * 32 + 16 + lg * 4];
  }

  const bf16x8* WoF = (const bf16x8*)WoB;
  float vals[8][4];  // [ct][r]
#pragma unroll
  for (int ct = 0; ct < 8; ++ct) {
    f32x4 acc = {0.f, 0.f, 0.f, 0.f};
#pragma unroll
    for (int ks = 0; ks < 4; ++ks) {
      bf16x8 b = WoF[(ct * 4 + ks) * 64 + l];
      acc = __builtin_amdgcn_mfma_f32_16x16x32_bf16(af[ks].v, b, acc, 0, 0, 0);
    }
    float boc = bo[ct * 16 + lr];
#pragma unroll
    for (int r = 0; r < 4; ++r) {
      int row = node0 + row0 + lg * 4 + r;
      vals[ct][r] = acc[r] + boc + X[(int64_t)row * DIM + ct * 16 + lr];
    }
  }

  // LN: row (lg*4+r) lives across the 16 lanes sharing lg
  float s1[4], s2[4];
#pragma unroll
  for (int r = 0; r < 4; ++r) {
    float a = 0.f, b2 = 0.f;
#pragma unroll
    for (int ct = 0; ct < 8; ++ct) {
      a += vals[ct][r];
      b2 += vals[ct][r] * vals[ct][r];
    }
    s1[r] = a;
    s2[r] = b2;
  }
#pragma unroll
  for (int off = 1; off < 16; off <<= 1) {
#pragma unroll
    for (int r = 0; r < 4; ++r) {
      s1[r] += __shfl_xor(s1[r], off);
      s2[r] += __shfl_xor(s2[r], off);
    }
  }
  float mu[4], rs[4];
#pragma unroll
  for (int r = 0; r < 4; ++r) {
    mu[r] = s1[r] * (1.0f / DIM);
    float var = s2[r] * (1.0f / DIM) - mu[r] * mu[r];
    rs[r] = rsqrtf(var + 1e-5f);
  }
#pragma unroll
  for (int ct = 0; ct < 8; ++ct) {
    float gm = gamma[ct * 16 + lr], bt = beta[ct * 16 + lr];
#pragma unroll
    for (int r = 0; r < 4; ++r) {
      int row = node0 + row0 + lg * 4 + r;
      out[(int64_t)row * DIM + ct * 16 + lr] =
          (vals[ct][r] - mu[r]) * rs[r] * gm + bt;
    }
  }
}

extern "C" void kernel_launch(void* const* d_in, const int* in_sizes, int n_in,
                              void* d_out, int out_size, void* d_ws,
                              size_t ws_size, hipStream_t stream) {
  const float* X     = (const float*)d_in[0];
  const int*   eidx  = (const int*)d_in[1];
  const float* Wq    = (const float*)d_in[2];
  const float* bq    = (const float*)d_in[3];
  const float* Wk    = (const float*)d_in[4];
  const float* bk    = (const float*)d_in[5];
  const float* Wv    = (const float*)d_in[6];
  const float* bv    = (const float*)d_in[7];
  const float* attn  = (const float*)d_in[8];
  const float* Wo    = (const float*)d_in[9];
  const float* bo    = (const float*)d_in[10];
  const float* gamma = (const float*)d_in[11];
  const float* beta  = (const float*)d_in[12];
  float* out = (float*)d_out;

  float* ws    = (float*)d_ws;
  ushort_t* Wb  = (ushort_t*)ws;          // 16384 ushorts (Wv frags)
  ushort_t* WoB = Wb + 16384;             // 16384 ushorts (Wo frags)
  float* AqT  = ws + 16384;               // 1024, layout [h][128]
  float* AkT  = AqT + 1024;               // 1024
  float* cvec = AkT + 1024;               // 16
  float* aqv  = cvec + 16;                // BN*NH
  float* akv  = aqv + (int64_t)BN * NH;   // BN*NH
  ushort_t* V   = (ushort_t*)(akv + (int64_t)BN * NH);  // BN*DIM bf16
  ushort_t* agg = V + (int64_t)BN * DIM;                // BN*DIM bf16
  int* cursor = (int*)(agg + (int64_t)BN * DIM);        // BN
  int* bucket = cursor + BN;                            // BN*CAP

  k_init<<<NB + 1, 256, 0, stream>>>(Wq, bq, Wk, bk, attn, Wv, Wo, AqT, AkT,
                                     cvec, Wb, WoB, cursor);
  k_fat<<<PROJ_BLOCKS + SCAT_BLOCKS, 256, 0, stream>>>(
      X, Wb, bv, AqT, AkT, cvec, aqv, akv, V, eidx, cursor, bucket);
  k_gather<<<BN / 4, 256, 0, stream>>>(bucket, cursor, aqv, akv, V, agg);
  k_out<<<BN / 64, 256, 0, stream>>>(agg, WoB, X, bo, gamma, beta, out);
}